// Round 3
// baseline (885.286 us; speedup 1.0000x reference)
//
#include <hip/hip_runtime.h>

#define B_ 8
#define T_ 1024
#define C_ 1024
#define H_ 16
#define D_ 64
#define TI_ 256
#define FF_ 4096
#define BT_ (B_*T_)
#define BTI_ (B_*TI_)

typedef __bf16 bf16x8 __attribute__((ext_vector_type(8)));
typedef float f32x4 __attribute__((ext_vector_type(4)));
typedef float f32x16 __attribute__((ext_vector_type(16)));

__device__ __forceinline__ unsigned short f2bf(float f){
  unsigned u = __float_as_uint(f);
  u += 0x7fffu + ((u>>16)&1u);
  return (unsigned short)(u>>16);
}

// async global->LDS, 16B per lane; LDS dest = wave-uniform base + lane*16
__device__ __forceinline__ void cp16(const void* g, void* l){
  __builtin_amdgcn_global_load_lds(
      (const __attribute__((address_space(1))) unsigned int*)(unsigned long long)g,
      (__attribute__((address_space(3))) unsigned int*)(unsigned long long)l,
      16, 0, 0);
}

// ---------------------------------------------------------------------------
// GEMM: C[M,N] = A[M,K](bf16) @ Bt[N,K]^T(bf16) + bias, fused epilogue.
// mode 0: out bf16 = v+bias ; mode 1: out bf16 = gelu(v+bias)
// mode 2: out f32 = resid + v + bias
// 128x128 tile, BK=64, XOR-swizzled LDS chunks, mfma_f32_32x32x16_bf16.
// ---------------------------------------------------------------------------
__global__ __launch_bounds__(256) void gemm_bt(
    const unsigned short* __restrict__ A,
    const unsigned short* __restrict__ Bt,
    const float* __restrict__ bias,
    const float* __restrict__ resid,
    void* __restrict__ outp,
    int M, int N, int K, int mode)
{
  __shared__ unsigned short sA[128*64];
  __shared__ unsigned short sB[128*64];
  const int tid  = threadIdx.x;
  const int wid  = tid >> 6;
  const int lane = tid & 63;
  const int l32  = lane & 31;
  const int khalf = lane >> 5;

  const int row0 = blockIdx.y * 128;
  const int col0 = blockIdx.x * 128;
  const int wr = (wid >> 1) * 64;
  const int wc = (wid & 1) * 64;

  f32x16 acc[2][2];
#pragma unroll
  for (int i=0;i<2;i++)
#pragma unroll
    for (int j=0;j<2;j++)
#pragma unroll
      for (int r=0;r<16;r++) acc[i][j][r] = 0.f;

  for (int k0 = 0; k0 < K; k0 += 64){
    if (k0) __syncthreads();
#pragma unroll
    for (int r=0;r<8;r++){
      int chunk = wid*8 + r;          // 0..31 ; <16 => A-tile, else B-tile
      int cA = chunk & 15;
      int slot = cA*64 + lane;        // 16B slot within tile
      int row = slot >> 3;
      int cc = (slot & 7) ^ (row & 7);
      if (chunk < 16)
        cp16(A  + (size_t)(row0+row)*K + (k0 + cc*8), sA + cA*512);
      else
        cp16(Bt + (size_t)(col0+row)*K + (k0 + cc*8), sB + cA*512);
    }
    __syncthreads();
    const char* sAb = (const char*)sA;
    const char* sBb = (const char*)sB;
#pragma unroll
    for (int kk=0;kk<4;kk++){
      bf16x8 af[2], bfb[2];
#pragma unroll
      for (int i=0;i<2;i++){
        int rr = wr + i*32 + l32;
        af[i] = *(const bf16x8*)(sAb + rr*128 + ((((kk<<1)+khalf) ^ (rr&7))<<4));
      }
#pragma unroll
      for (int j=0;j<2;j++){
        int rr = wc + j*32 + l32;
        bfb[j] = *(const bf16x8*)(sBb + rr*128 + ((((kk<<1)+khalf) ^ (rr&7))<<4));
      }
#pragma unroll
      for (int i=0;i<2;i++)
#pragma unroll
        for (int j=0;j<2;j++)
          acc[i][j] = __builtin_amdgcn_mfma_f32_32x32x16_bf16(af[i], bfb[j], acc[i][j], 0, 0, 0);
    }
  }

  // epilogue: C/D layout col=lane&31, row=(reg&3)+8*(reg>>2)+4*(lane>>5)
#pragma unroll
  for (int j=0;j<2;j++){
    int gc = col0 + wc + j*32 + l32;
    float bz = bias[gc];
#pragma unroll
    for (int i=0;i<2;i++){
      int gr_base = row0 + wr + i*32 + 4*khalf;
#pragma unroll
      for (int reg=0; reg<16; ++reg){
        int gr = gr_base + (reg&3) + 8*(reg>>2);
        float v = acc[i][j][reg] + bz;
        size_t idx = (size_t)gr*N + gc;
        if (mode == 0){
          ((unsigned short*)outp)[idx] = f2bf(v);
        } else if (mode == 1){
          float w = 1.5957691216057308f*(v + 0.044715f*v*v*v);
          float g = v / (1.f + __expf(-w));
          ((unsigned short*)outp)[idx] = f2bf(g);
        } else {
          ((float*)outp)[idx] = resid[idx] + v;
        }
      }
    }
  }
}

// ---------------------------------------------------------------------------
// LayerNorm over C=1024, fp32 in -> bf16 out. One block per row.
// ---------------------------------------------------------------------------
__global__ __launch_bounds__(256) void ln_fwd(
    const float* __restrict__ x, const float* __restrict__ g,
    const float* __restrict__ b, unsigned short* __restrict__ out)
{
  int row = blockIdx.x, t = threadIdx.x;
  const float4* xv = (const float4*)(x + (size_t)row*C_);
  float4 v = xv[t];
  float s  = v.x+v.y+v.z+v.w;
  float ss = v.x*v.x + v.y*v.y + v.z*v.z + v.w*v.w;
#pragma unroll
  for (int o=32;o>0;o>>=1){ s += __shfl_down(s,o); ss += __shfl_down(ss,o); }
  __shared__ float red[16];
  int wid = t>>6, lane = t&63;
  if (lane==0){ red[wid]=s; red[8+wid]=ss; }
  __syncthreads();
  if (t==0){
    red[0] = red[0]+red[1]+red[2]+red[3];
    red[8] = red[8]+red[9]+red[10]+red[11];
  }
  __syncthreads();
  float mu  = red[0] * (1.f/C_);
  float var = red[8] * (1.f/C_) - mu*mu;
  float rstd = rsqrtf(var + 1e-5f);
  float4 gv = ((const float4*)g)[t];
  float4 bv = ((const float4*)b)[t];
  ushort4 o;
  o.x = f2bf((v.x-mu)*rstd*gv.x + bv.x);
  o.y = f2bf((v.y-mu)*rstd*gv.y + bv.y);
  o.z = f2bf((v.z-mu)*rstd*gv.z + bv.z);
  o.w = f2bf((v.w-mu)*rstd*gv.w + bv.w);
  ((ushort4*)(out + (size_t)row*C_))[t] = o;
}

// ---------------------------------------------------------------------------
// Weight transpose+convert: W[Kd,Nd] fp32 -> Wt[Nd,Kd] bf16. 32x32 LDS tile.
// ---------------------------------------------------------------------------
__global__ void wconv_t(const float* __restrict__ W, unsigned short* __restrict__ Wt,
                        int Kd, int Nd)
{
  __shared__ float tile[32][33];
  int tx = threadIdx.x, ty = threadIdx.y;   // 32 x 8
  int n0 = blockIdx.x*32, k0 = blockIdx.y*32;
#pragma unroll
  for (int j=0;j<4;j++)
    tile[ty+8*j][tx] = W[(size_t)(k0+ty+8*j)*Nd + (n0+tx)];
  __syncthreads();
#pragma unroll
  for (int j=0;j<4;j++)
    Wt[(size_t)(n0+ty+8*j)*Kd + (k0+tx)] = f2bf(tile[tx][ty+8*j]);
}

// five 1024x1024 transposes in one launch (z selects the matrix)
__global__ void wconv_t5(const float* W0, const float* W1, const float* W2,
                         const float* W3, const float* W4,
                         unsigned short* O0, unsigned short* O1, unsigned short* O2,
                         unsigned short* O3, unsigned short* O4)
{
  __shared__ float tile[32][33];
  const float* Ws[5] = {W0,W1,W2,W3,W4};
  unsigned short* Os[5] = {O0,O1,O2,O3,O4};
  const float* W = Ws[blockIdx.z];
  unsigned short* Wt = Os[blockIdx.z];
  int tx = threadIdx.x, ty = threadIdx.y;
  int n0 = blockIdx.x*32, k0 = blockIdx.y*32;
#pragma unroll
  for (int j=0;j<4;j++)
    tile[ty+8*j][tx] = W[(size_t)(k0+ty+8*j)*1024 + (n0+tx)];
  __syncthreads();
#pragma unroll
  for (int j=0;j<4;j++)
    Wt[(size_t)(n0+ty+8*j)*1024 + (k0+tx)] = f2bf(tile[tx][ty+8*j]);
}

__global__ void conv_bf16(const float* __restrict__ X, unsigned short* __restrict__ Y, int n4)
{
  int i = blockIdx.x*256 + threadIdx.x;
  if (i < n4){
    float4 v = ((const float4*)X)[i];
    ushort4 o; o.x=f2bf(v.x); o.y=f2bf(v.y); o.z=f2bf(v.z); o.w=f2bf(v.w);
    ((ushort4*)Y)[i] = o;
  }
}

// ---------------------------------------------------------------------------
// Fused flash attention v3: 128 q-rows/block (2 subtiles of 16 per wave),
// kv-tile 64, double-buffered LDS, async K prefetch via global_load_lds
// (issued right after the barrier so the vmcnt drain overlaps compute),
// V prefetched into regs and transpose-written to the alternate buffer.
// ---------------------------------------------------------------------------
__global__ __launch_bounds__(256,3) void attn_fwd(
    const unsigned short* __restrict__ Q, int ldq,
    const unsigned short* __restrict__ Kp, const unsigned short* __restrict__ Vp, int ldkv,
    int kvT, int Skv, int Tq, int causal,
    unsigned short* __restrict__ Out, int ldo, float scale)
{
  __shared__ unsigned short sK[2][64*64];
  __shared__ unsigned short sVT[2][64*64];
  __shared__ unsigned short sP[8*16*64];   // 4 waves x 2 subtiles x 16x64
  const int tid = threadIdx.x;
  const int wid = tid >> 6;
  const int lane = tid & 63;
  const int quad = lane >> 4;
  const int l16 = lane & 15;
  const int qt = gridDim.x - 1 - blockIdx.x;   // longest (causal) blocks first
  const int h = blockIdx.y, b = blockIdx.z;
  const int hoff = h * D_;
  const float c2 = scale * 1.4426950408889634f;  // scale * log2(e)

  // Q fragments for both subtiles
  bf16x8 qf[2][2];
#pragma unroll
  for (int s=0;s<2;s++){
    int qrow = qt*128 + s*64 + wid*16 + l16;
    const unsigned short* qb = Q + (size_t)(b*Tq + qrow)*ldq + hoff;
    qf[s][0] = *(const bf16x8*)(qb + quad*8);
    qf[s][1] = *(const bf16x8*)(qb + 32 + quad*8);
  }

  f32x4 O[2][4];
#pragma unroll
  for (int s=0;s<2;s++)
#pragma unroll
    for (int j=0;j<4;j++) O[s][j] = (f32x4){0.f,0.f,0.f,0.f};
  float mrun[2][4], lrun[2][4];
#pragma unroll
  for (int s=0;s<2;s++)
#pragma unroll
    for (int r=0;r<4;r++){ mrun[s][r] = -1e30f; lrun[s][r] = 0.f; }

  const int nkb = causal ? (2*qt + 2) : ((Skv + 63) >> 6);

  uint4 vreg0, vreg1;
  const int vsrow = lane;             // V staging: this lane's source row
  const int vdbase = wid*16;

  // ---- prologue: stage tile 0
  {
    const unsigned short* gv = Vp + (size_t)(b*kvT + vsrow)*ldkv + hoff + vdbase;
    vreg0 = *(const uint4*)gv; vreg1 = *(const uint4*)(gv+8);
#pragma unroll
    for (int ss=0; ss<2; ++ss){
      int slot = tid + ss*256;
      int srow = slot >> 3;
      int cc = (slot & 7) ^ (srow & 7);
      cp16(Kp + (size_t)(b*kvT + srow)*ldkv + hoff + cc*8,
           sK[0] + (size_t)(wid*64 + ss*256)*8);
    }
    unsigned short vals[16];
    *(uint4*)vals = vreg0; *(uint4*)(vals+8) = vreg1;
    int chunk = vsrow >> 3, sb = (vsrow & 7)*2;
#pragma unroll
    for (int jj=0; jj<16; ++jj){
      int d = vdbase + jj;
      *(unsigned short*)((char*)sVT[0] + d*128 + ((chunk ^ (d&7))<<4) + sb) = vals[jj];
    }
  }
  __syncthreads();

  int cur = 0;
  for (int kb=0; kb<nkb; ++kb){
    const bool pre = (kb+1 < nkb);
    if (pre){
      // prefetch V into regs, K into LDS[cur^1] — both overlap this tile's compute
      const unsigned short* gv = Vp + (size_t)(b*kvT + (kb+1)*64 + vsrow)*ldkv + hoff + vdbase;
      vreg0 = *(const uint4*)gv; vreg1 = *(const uint4*)(gv+8);
#pragma unroll
      for (int ss=0; ss<2; ++ss){
        int slot = tid + ss*256;
        int srow = slot >> 3;
        int cc = (slot & 7) ^ (srow & 7);
        cp16(Kp + (size_t)(b*kvT + (kb+1)*64 + srow)*ldkv + hoff + cc*8,
             sK[cur^1] + (size_t)(wid*64 + ss*256)*8);
      }
    }
    const char* sKb = (const char*)sK[cur];
    const char* sVb = (const char*)sVT[cur];

#pragma unroll
    for (int s=0; s<2; ++s){
      const int qb0 = qt*128 + s*64;
      if (causal && kb*64 > qb0 + 63) continue;  // subtile fully masked (uniform)

      f32x4 sacc[4];
#pragma unroll
      for (int j=0;j<4;j++) sacc[j] = (f32x4){0.f,0.f,0.f,0.f};
#pragma unroll
      for (int j=0;j<4;j++){
        int krow = j*16 + l16;
#pragma unroll
        for (int kk=0;kk<2;kk++){
          bf16x8 kf = *(const bf16x8*)(sKb + krow*128 + (((kk*4+quad) ^ (krow&7))<<4));
          sacc[j] = __builtin_amdgcn_mfma_f32_16x16x32_bf16(qf[s][kk], kf, sacc[j], 0, 0, 0);
        }
      }
      const int qa0 = qb0 + wid*16 + quad*4;
      float sc[4][4];
#pragma unroll
      for (int j=0;j<4;j++){
        int key = kb*64 + j*16 + l16;
#pragma unroll
        for (int r=0;r<4;r++){
          float v = sacc[j][r];
          if (causal && key > qa0 + r) v = -1e30f;
          sc[j][r] = v;
        }
      }
      float mnew[4], alpha[4], rs[4];
#pragma unroll
      for (int r=0;r<4;r++){
        float m = fmaxf(fmaxf(sc[0][r], sc[1][r]), fmaxf(sc[2][r], sc[3][r]));
#pragma unroll
        for (int msk=1; msk<16; msk<<=1) m = fmaxf(m, __shfl_xor(m, msk));
        mnew[r] = fmaxf(mrun[s][r], m);
        alpha[r] = exp2f((mrun[s][r] - mnew[r]) * c2);
        mrun[s][r] = mnew[r];
        rs[r] = 0.f;
      }
      char* sPw = (char*)sP + (wid*2 + s)*2048;
#pragma unroll
      for (int j=0;j<4;j++){
#pragma unroll
        for (int r=0;r<4;r++){
          float p = exp2f((sc[j][r] - mnew[r]) * c2);
          rs[r] += p;
          int prow = quad*4 + r;
          int cole = j*16 + l16;
          *(unsigned short*)(sPw + prow*128 + (((cole>>3) ^ (prow&7))<<4) + (cole&7)*2) = f2bf(p);
        }
      }
#pragma unroll
      for (int r=0;r<4;r++){
#pragma unroll
        for (int msk=1; msk<16; msk<<=1) rs[r] += __shfl_xor(rs[r], msk);
        lrun[s][r] = lrun[s][r]*alpha[r] + rs[r];
      }
#pragma unroll
      for (int j=0;j<4;j++){
        O[s][j][0] *= alpha[0]; O[s][j][1] *= alpha[1];
        O[s][j][2] *= alpha[2]; O[s][j][3] *= alpha[3];
      }
      bf16x8 pf[2];
#pragma unroll
      for (int kk=0;kk<2;kk++)
        pf[kk] = *(const bf16x8*)(sPw + l16*128 + (((kk*4+quad) ^ (l16&7))<<4));
#pragma unroll
      for (int j=0;j<4;j++){
        int vrow = j*16 + l16;
#pragma unroll
        for (int kk=0;kk<2;kk++){
          bf16x8 vf = *(const bf16x8*)(sVb + vrow*128 + (((kk*4+quad) ^ (vrow&7))<<4));
          O[s][j] = __builtin_amdgcn_mfma_f32_16x16x32_bf16(pf[kk], vf, O[s][j], 0, 0, 0);
        }
      }
    }

    if (pre){
      unsigned short vals[16];
      *(uint4*)vals = vreg0; *(uint4*)(vals+8) = vreg1;
      int chunk = vsrow >> 3, sb = (vsrow & 7)*2;
#pragma unroll
      for (int jj=0; jj<16; ++jj){
        int d = vdbase + jj;
        *(unsigned short*)((char*)sVT[cur^1] + d*128 + ((chunk ^ (d&7))<<4) + sb) = vals[jj];
      }
    }
    __syncthreads();
    cur ^= 1;
  }

#pragma unroll
  for (int s=0;s<2;s++){
#pragma unroll
    for (int j=0;j<4;j++){
#pragma unroll
      for (int r=0;r<4;r++){
        int qa = qt*128 + s*64 + wid*16 + quad*4 + r;
        float o = O[s][j][r] / lrun[s][r];
        Out[(size_t)(b*Tq + qa)*ldo + hoff + j*16 + l16] = f2bf(o);
      }
    }
  }
}

// ---------------------------------------------------------------------------
extern "C" void kernel_launch(void* const* d_in, const int* in_sizes, int n_in,
                              void* d_out, int out_size, void* d_ws, size_t ws_size,
                              hipStream_t stream)
{
  const float* x       = (const float*)d_in[0];
  const float* ximg    = (const float*)d_in[1];
  const float* ln1_g   = (const float*)d_in[2];
  const float* ln1_b   = (const float*)d_in[3];
  const float* ln2_g   = (const float*)d_in[4];
  const float* ln2_b   = (const float*)d_in[5];
  const float* W_attn  = (const float*)d_in[6];
  const float* b_attn  = (const float*)d_in[7];
  const float* W_aproj = (const float*)d_in[8];
  const float* b_aproj = (const float*)d_in[9];
  const float* Wq = (const float*)d_in[10];
  const float* bq = (const float*)d_in[11];
  const float* Wk = (const float*)d_in[12];
  const float* bk = (const float*)d_in[13];
  const float* Wv = (const float*)d_in[14];
  const float* bv = (const float*)d_in[15];
  const float* Wcproj  = (const float*)d_in[16];
  const float* bcproj  = (const float*)d_in[17];
  const float* W_fc    = (const float*)d_in[18];
  const float* b_fc    = (const float*)d_in[19];
  const float* W_mproj = (const float*)d_in[20];
  const float* b_mproj = (const float*)d_in[21];

  char* ws = (char*)d_ws;
  unsigned short* wt_attn  = (unsigned short*)(ws + 0);
  unsigned short* wt_aproj = (unsigned short*)(ws + 6291456);
  unsigned short* wt_q     = (unsigned short*)(ws + 8388608);
  unsigned short* wt_k     = (unsigned short*)(ws + 10485760);
  unsigned short* wt_v     = (unsigned short*)(ws + 12582912);
  unsigned short* wt_cproj = (unsigned short*)(ws + 14680064);
  unsigned short* wt_fc    = (unsigned short*)(ws + 16777216);
  unsigned short* wt_mproj = (unsigned short*)(ws + 25165824);
  unsigned short* ximg_bf  = (unsigned short*)(ws + 33554432);
  float*          xcur     = (float*)(ws + 37748736);
  unsigned short* h_bf     = (unsigned short*)(ws + 71303168);
  unsigned short* qkv      = (unsigned short*)(ws + 88080384);
  unsigned short* att_out  = (unsigned short*)(ws + 88080384 + 50331648);
  unsigned short* u_bf     = (unsigned short*)(ws + 88080384);   // aliases qkv+att_out (dead by then)
  unsigned short* q2   = (unsigned short*)(ws + 155189248);
  unsigned short* k2v2 = (unsigned short*)(ws + 171966464);      // [2048 rows][2048] k|v
  unsigned short* ca   = (unsigned short*)(ws + 180355072);
  float*          bkv  = (float*)(ws + 197132288);               // concat bk|bv

  dim3 tb(32,8);
  wconv_t5<<<dim3(32,32,5), tb, 0, stream>>>(W_aproj, Wq, Wk, Wv, Wcproj,
                                             wt_aproj, wt_q, wt_k, wt_v, wt_cproj);
  wconv_t<<<dim3(96,32),  tb, 0, stream>>>(W_attn,  wt_attn,  1024, 3072);
  wconv_t<<<dim3(128,32), tb, 0, stream>>>(W_fc,    wt_fc,    1024, 4096);
  wconv_t<<<dim3(32,128), tb, 0, stream>>>(W_mproj, wt_mproj, 4096, 1024);
  conv_bf16<<<BTI_*C_/4/256, 256, 0, stream>>>(ximg, ximg_bf, BTI_*C_/4);
  hipMemcpyAsync(xcur, x, (size_t)BT_*C_*4, hipMemcpyDeviceToDevice, stream);
  hipMemcpyAsync(bkv,        bk, 4096, hipMemcpyDeviceToDevice, stream);
  hipMemcpyAsync(bkv + 1024, bv, 4096, hipMemcpyDeviceToDevice, stream);

  // self-attention
  ln_fwd<<<BT_, 256, 0, stream>>>(x, ln1_g, ln1_b, h_bf);
  gemm_bt<<<dim3(24,64), 256, 0, stream>>>(h_bf, wt_attn, b_attn, nullptr, qkv, BT_, 3072, 1024, 0);
  attn_fwd<<<dim3(8,H_,B_), 256, 0, stream>>>(qkv, 3072, qkv+1024, qkv+2048, 3072,
                                              T_, T_, T_, 1, att_out, C_, 0.125f);
  gemm_bt<<<dim3(8,64), 256, 0, stream>>>(att_out, wt_aproj, b_aproj, xcur, xcur, BT_, 1024, 1024, 2);

  // cross-attention
  ln_fwd<<<BT_, 256, 0, stream>>>(xcur, ln1_g, ln1_b, h_bf);
  gemm_bt<<<dim3(8,64), 256, 0, stream>>>(h_bf, wt_q, bq, nullptr, q2, BT_, 1024, 1024, 0);
  gemm_bt<<<dim3(16,16), 256, 0, stream>>>(ximg_bf, wt_k, bkv, nullptr, k2v2, BTI_, 2048, 1024, 0);
  attn_fwd<<<dim3(8,H_,B_), 256, 0, stream>>>(q2, 1024, k2v2, k2v2+1024, 2048,
                                              TI_, TI_, T_, 0, ca, C_, 0.125f);
  gemm_bt<<<dim3(8,64), 256, 0, stream>>>(ca, wt_cproj, bcproj, xcur, xcur, BT_, 1024, 1024, 2);

  // MLP
  ln_fwd<<<BT_, 256, 0, stream>>>(xcur, ln2_g, ln2_b, h_bf);
  gemm_bt<<<dim3(32,64), 256, 0, stream>>>(h_bf, wt_fc, b_fc, nullptr, u_bf, BT_, 4096, 1024, 1);
  gemm_bt<<<dim3(8,64), 256, 0, stream>>>(u_bf, wt_mproj, b_mproj, xcur, (float*)d_out, BT_, 1024, 4096, 2);
}

// Round 4
// 839.220 us; speedup vs baseline: 1.0549x; 1.0549x over previous
//
#include <hip/hip_runtime.h>

#define B_ 8
#define T_ 1024
#define C_ 1024
#define H_ 16
#define D_ 64
#define TI_ 256
#define FF_ 4096
#define BT_ (B_*T_)
#define BTI_ (B_*TI_)

typedef __bf16 bf16x8 __attribute__((ext_vector_type(8)));
typedef float f32x4 __attribute__((ext_vector_type(4)));
typedef float f32x16 __attribute__((ext_vector_type(16)));

__device__ __forceinline__ unsigned short f2bf(float f){
  unsigned u = __float_as_uint(f);
  u += 0x7fffu + ((u>>16)&1u);
  return (unsigned short)(u>>16);
}

// async global->LDS, 16B per lane; LDS dest = wave-uniform base + lane*16
__device__ __forceinline__ void cp16(const void* g, void* l){
  __builtin_amdgcn_global_load_lds(
      (const __attribute__((address_space(1))) unsigned int*)(unsigned long long)g,
      (__attribute__((address_space(3))) unsigned int*)(unsigned long long)l,
      16, 0, 0);
}

// ---------------------------------------------------------------------------
// GEMM: C[M,N] = A[M,K](bf16) @ Bt[N,K]^T(bf16) + bias, fused epilogue.
// mode 0: out bf16 = v+bias ; mode 1: out bf16 = gelu(v+bias)
// mode 2: out f32 = resid + v + bias
// mode 3: out bf16 = v+bias, head-major permute [b,h,kind,t,d]
//         (kind = gc>>10, h=(gc>>6)&15, d=gc&63, b=gr>>tshift, t=gr&mask)
// 128x128 tile, BK=64, XOR-swizzled LDS chunks, mfma_f32_32x32x16_bf16.
// ---------------------------------------------------------------------------
__global__ __launch_bounds__(256) void gemm_bt(
    const unsigned short* __restrict__ A,
    const unsigned short* __restrict__ Bt,
    const float* __restrict__ bias,
    const float* __restrict__ resid,
    void* __restrict__ outp,
    int M, int N, int K, int mode, int nkind, int tshift)
{
  __shared__ unsigned short sA[128*64];
  __shared__ unsigned short sB[128*64];
  const int tid  = threadIdx.x;
  const int wid  = tid >> 6;
  const int lane = tid & 63;
  const int l32  = lane & 31;
  const int khalf = lane >> 5;

  const int row0 = blockIdx.y * 128;
  const int col0 = blockIdx.x * 128;
  const int wr = (wid >> 1) * 64;
  const int wc = (wid & 1) * 64;

  f32x16 acc[2][2];
#pragma unroll
  for (int i=0;i<2;i++)
#pragma unroll
    for (int j=0;j<2;j++)
#pragma unroll
      for (int r=0;r<16;r++) acc[i][j][r] = 0.f;

  for (int k0 = 0; k0 < K; k0 += 64){
    if (k0) __syncthreads();
#pragma unroll
    for (int r=0;r<8;r++){
      int chunk = wid*8 + r;          // 0..31 ; <16 => A-tile, else B-tile
      int cA = chunk & 15;
      int slot = cA*64 + lane;        // 16B slot within tile
      int row = slot >> 3;
      int cc = (slot & 7) ^ (row & 7);
      if (chunk < 16)
        cp16(A  + (size_t)(row0+row)*K + (k0 + cc*8), sA + cA*512);
      else
        cp16(Bt + (size_t)(col0+row)*K + (k0 + cc*8), sB + cA*512);
    }
    __syncthreads();
    const char* sAb = (const char*)sA;
    const char* sBb = (const char*)sB;
#pragma unroll
    for (int kk=0;kk<4;kk++){
      bf16x8 af[2], bfb[2];
#pragma unroll
      for (int i=0;i<2;i++){
        int rr = wr + i*32 + l32;
        af[i] = *(const bf16x8*)(sAb + rr*128 + ((((kk<<1)+khalf) ^ (rr&7))<<4));
      }
#pragma unroll
      for (int j=0;j<2;j++){
        int rr = wc + j*32 + l32;
        bfb[j] = *(const bf16x8*)(sBb + rr*128 + ((((kk<<1)+khalf) ^ (rr&7))<<4));
      }
#pragma unroll
      for (int i=0;i<2;i++)
#pragma unroll
        for (int j=0;j<2;j++)
          acc[i][j] = __builtin_amdgcn_mfma_f32_32x32x16_bf16(af[i], bfb[j], acc[i][j], 0, 0, 0);
    }
  }

  // epilogue: C/D layout col=lane&31, row=(reg&3)+8*(reg>>2)+4*(lane>>5)
#pragma unroll
  for (int j=0;j<2;j++){
    int gc = col0 + wc + j*32 + l32;
    float bz = bias[gc];
#pragma unroll
    for (int i=0;i<2;i++){
      int gr_base = row0 + wr + i*32 + 4*khalf;
#pragma unroll
      for (int reg=0; reg<16; ++reg){
        int gr = gr_base + (reg&3) + 8*(reg>>2);
        float v = acc[i][j][reg] + bz;
        if (mode == 0){
          ((unsigned short*)outp)[(size_t)gr*N + gc] = f2bf(v);
        } else if (mode == 1){
          float w = 1.5957691216057308f*(v + 0.044715f*v*v*v);
          float g = v / (1.f + __expf(-w));
          ((unsigned short*)outp)[(size_t)gr*N + gc] = f2bf(g);
        } else if (mode == 2){
          size_t idx = (size_t)gr*N + gc;
          ((float*)outp)[idx] = resid[idx] + v;
        } else {
          int kind = gc >> 10;
          int hc = gc & 1023;
          int hh = hc >> 6;
          int d  = hc & 63;
          int bb = gr >> tshift;
          int tt = gr & ((1<<tshift)-1);
          size_t oidx = ((((size_t)(bb*16 + hh)*nkind + kind) << tshift) + tt)*64 + d;
          ((unsigned short*)outp)[oidx] = f2bf(v);
        }
      }
    }
  }
}

// ---------------------------------------------------------------------------
// LayerNorm over C=1024, fp32 in -> bf16 out. One block per row.
// ---------------------------------------------------------------------------
__global__ __launch_bounds__(256) void ln_fwd(
    const float* __restrict__ x, const float* __restrict__ g,
    const float* __restrict__ b, unsigned short* __restrict__ out)
{
  int row = blockIdx.x, t = threadIdx.x;
  const float4* xv = (const float4*)(x + (size_t)row*C_);
  float4 v = xv[t];
  float s  = v.x+v.y+v.z+v.w;
  float ss = v.x*v.x + v.y*v.y + v.z*v.z + v.w*v.w;
#pragma unroll
  for (int o=32;o>0;o>>=1){ s += __shfl_down(s,o); ss += __shfl_down(ss,o); }
  __shared__ float red[16];
  int wid = t>>6, lane = t&63;
  if (lane==0){ red[wid]=s; red[8+wid]=ss; }
  __syncthreads();
  if (t==0){
    red[0] = red[0]+red[1]+red[2]+red[3];
    red[8] = red[8]+red[9]+red[10]+red[11];
  }
  __syncthreads();
  float mu  = red[0] * (1.f/C_);
  float var = red[8] * (1.f/C_) - mu*mu;
  float rstd = rsqrtf(var + 1e-5f);
  float4 gv = ((const float4*)g)[t];
  float4 bv = ((const float4*)b)[t];
  ushort4 o;
  o.x = f2bf((v.x-mu)*rstd*gv.x + bv.x);
  o.y = f2bf((v.y-mu)*rstd*gv.y + bv.y);
  o.z = f2bf((v.z-mu)*rstd*gv.z + bv.z);
  o.w = f2bf((v.w-mu)*rstd*gv.w + bv.w);
  ((ushort4*)(out + (size_t)row*C_))[t] = o;
}

// ---------------------------------------------------------------------------
// Weight transpose+convert: W[Kd,Nd] fp32 -> Wt[Nd,Kd] bf16. 32x32 LDS tile.
// ---------------------------------------------------------------------------
__global__ void wconv_t(const float* __restrict__ W, unsigned short* __restrict__ Wt,
                        int Kd, int Nd)
{
  __shared__ float tile[32][33];
  int tx = threadIdx.x, ty = threadIdx.y;   // 32 x 8
  int n0 = blockIdx.x*32, k0 = blockIdx.y*32;
#pragma unroll
  for (int j=0;j<4;j++)
    tile[ty+8*j][tx] = W[(size_t)(k0+ty+8*j)*Nd + (n0+tx)];
  __syncthreads();
#pragma unroll
  for (int j=0;j<4;j++)
    Wt[(size_t)(n0+ty+8*j)*Kd + (k0+tx)] = f2bf(tile[tx][ty+8*j]);
}

// five 1024x1024 transposes in one launch (z selects the matrix)
__global__ void wconv_t5(const float* W0, const float* W1, const float* W2,
                         const float* W3, const float* W4,
                         unsigned short* O0, unsigned short* O1, unsigned short* O2,
                         unsigned short* O3, unsigned short* O4)
{
  __shared__ float tile[32][33];
  const float* Ws[5] = {W0,W1,W2,W3,W4};
  unsigned short* Os[5] = {O0,O1,O2,O3,O4};
  const float* W = Ws[blockIdx.z];
  unsigned short* Wt = Os[blockIdx.z];
  int tx = threadIdx.x, ty = threadIdx.y;
  int n0 = blockIdx.x*32, k0 = blockIdx.y*32;
#pragma unroll
  for (int j=0;j<4;j++)
    tile[ty+8*j][tx] = W[(size_t)(k0+ty+8*j)*1024 + (n0+tx)];
  __syncthreads();
#pragma unroll
  for (int j=0;j<4;j++)
    Wt[(size_t)(n0+ty+8*j)*1024 + (k0+tx)] = f2bf(tile[tx][ty+8*j]);
}

__global__ void conv_bf16(const float* __restrict__ X, unsigned short* __restrict__ Y, int n4)
{
  int i = blockIdx.x*256 + threadIdx.x;
  if (i < n4){
    float4 v = ((const float4*)X)[i];
    ushort4 o; o.x=f2bf(v.x); o.y=f2bf(v.y); o.z=f2bf(v.z); o.w=f2bf(v.w);
    ((ushort4*)Y)[i] = o;
  }
}

// ---------------------------------------------------------------------------
// Fused flash attention v4. Head-major inputs: Q/K/V per (b,h) contiguous
// [rows][64]. 1-D grid with XCD-grouping swizzle: all q-tiles of one (b,h)
// share (L mod 8) => same XCD L2 holds that head's K/V (256KB; 16 heads/XCD
// = 4MB = L2). 64 q-rows/block, kv-tile 64, single-buffer LDS (24KB,
// 6 blocks/CU), K via global_load_lds (contiguous 8KB tile), V transposed
// through registers, P via per-wave LDS round-trip, exp2f softmax.
// ---------------------------------------------------------------------------
__global__ __launch_bounds__(256) void attn_fwd(
    const unsigned short* __restrict__ Qb, unsigned int sQ,
    const unsigned short* __restrict__ Kb, const unsigned short* __restrict__ Vb,
    unsigned int sKV, int causal, int nkb_in,
    unsigned short* __restrict__ Out, float scale)
{
  __shared__ unsigned short sK[64*64];
  __shared__ unsigned short sV[64*64];
  __shared__ unsigned short sP[4*16*64];
  const int tid = threadIdx.x;
  const int wid = tid >> 6;
  const int lane = tid & 63;
  const int quad = lane >> 4;
  const int l16 = lane & 15;

  const int L = blockIdx.x;
  const int g  = (L & 7) + (L >> 7) * 8;   // (b,h) group, constant L%8 per group
  const int qt = 15 - ((L >> 3) & 15);     // longest causal blocks first
  const int b = g >> 4, h = g & 15;
  const float c2 = scale * 1.4426950408889634f;

  const unsigned short* Qp = Qb + (size_t)g * sQ;
  const unsigned short* Kp = Kb + (size_t)g * sKV;
  const unsigned short* Vp = Vb + (size_t)g * sKV;

  const int qrow = qt*64 + wid*16 + l16;
  const unsigned short* qb = Qp + (size_t)qrow*64;
  bf16x8 qf[2];
  qf[0] = *(const bf16x8*)(qb + quad*8);
  qf[1] = *(const bf16x8*)(qb + 32 + quad*8);

  f32x4 zero = {0.f,0.f,0.f,0.f};
  f32x4 O[4];
#pragma unroll
  for (int j=0;j<4;j++) O[j] = zero;
  float mrun[4], lrun[4];
#pragma unroll
  for (int r=0;r<4;r++){ mrun[r] = -1e30f; lrun[r] = 0.f; }

  const int nkb = causal ? (qt+1) : nkb_in;
  char* sPw = (char*)sP + wid*2048;

  for (int kb=0; kb<nkb; ++kb){
    if (kb) __syncthreads();
    // stage K: contiguous 8KB tile, swizzled chunks, via global_load_lds
#pragma unroll
    for (int ss=0; ss<2; ++ss){
      int slot = tid + ss*256;
      int srow = slot >> 3;
      int cc = (slot & 7) ^ (srow & 7);
      cp16(Kp + (size_t)kb*4096 + srow*64 + cc*8, sK + (size_t)(wid*64 + ss*256)*8);
    }
    // stage V transposed: sV[d][s]
    {
      int s_ = lane;
      int dbase = wid*16;
      const unsigned short* gv = Vp + (size_t)kb*4096 + s_*64 + dbase;
      unsigned short vals[16];
      *(uint4*)(vals)   = *(const uint4*)(gv);
      *(uint4*)(vals+8) = *(const uint4*)(gv+8);
      int chunk = s_ >> 3;
      int sb = (s_ & 7)*2;
#pragma unroll
      for (int jj=0; jj<16; ++jj){
        int d = dbase + jj;
        *(unsigned short*)((char*)sV + d*128 + ((chunk ^ (d&7))<<4) + sb) = vals[jj];
      }
    }
    __syncthreads();

    // S = Q K^T
    f32x4 sacc[4];
#pragma unroll
    for (int j=0;j<4;j++) sacc[j] = zero;
#pragma unroll
    for (int j=0;j<4;j++){
      int krow = j*16 + l16;
#pragma unroll
      for (int kk=0;kk<2;kk++){
        bf16x8 kf = *(const bf16x8*)((const char*)sK + krow*128 + (((kk*4+quad) ^ (krow&7))<<4));
        sacc[j] = __builtin_amdgcn_mfma_f32_16x16x32_bf16(qf[kk], kf, sacc[j], 0, 0, 0);
      }
    }
    const int qa0 = qt*64 + wid*16 + quad*4;
    float sc[4][4];
#pragma unroll
    for (int j=0;j<4;j++){
      int key = kb*64 + j*16 + l16;
#pragma unroll
      for (int r=0;r<4;r++){
        float v = sacc[j][r];
        if (causal && key > qa0 + r) v = -1e30f;
        sc[j][r] = v;
      }
    }
    float mnew[4], alpha[4], rs[4];
#pragma unroll
    for (int r=0;r<4;r++){
      float m = fmaxf(fmaxf(sc[0][r], sc[1][r]), fmaxf(sc[2][r], sc[3][r]));
#pragma unroll
      for (int msk=1; msk<16; msk<<=1) m = fmaxf(m, __shfl_xor(m, msk));
      mnew[r] = fmaxf(mrun[r], m);
      alpha[r] = exp2f((mrun[r] - mnew[r]) * c2);
      mrun[r] = mnew[r];
      rs[r] = 0.f;
    }
#pragma unroll
    for (int j=0;j<4;j++){
#pragma unroll
      for (int r=0;r<4;r++){
        float p = exp2f((sc[j][r] - mnew[r]) * c2);
        rs[r] += p;
        int prow = quad*4 + r;
        int cole = j*16 + l16;
        *(unsigned short*)(sPw + prow*128 + (((cole>>3) ^ (prow&7))<<4) + (cole&7)*2) = f2bf(p);
      }
    }
#pragma unroll
    for (int r=0;r<4;r++){
#pragma unroll
      for (int msk=1; msk<16; msk<<=1) rs[r] += __shfl_xor(rs[r], msk);
      lrun[r] = lrun[r]*alpha[r] + rs[r];
    }
#pragma unroll
    for (int j=0;j<4;j++){
      O[j][0] *= alpha[0]; O[j][1] *= alpha[1];
      O[j][2] *= alpha[2]; O[j][3] *= alpha[3];
    }
    // O += P V
    bf16x8 pf[2];
#pragma unroll
    for (int kk=0;kk<2;kk++)
      pf[kk] = *(const bf16x8*)(sPw + l16*128 + (((kk*4+quad) ^ (l16&7))<<4));
#pragma unroll
    for (int j=0;j<4;j++){
      int vrow = j*16 + l16;
#pragma unroll
      for (int kk=0;kk<2;kk++){
        bf16x8 vf = *(const bf16x8*)((const char*)sV + vrow*128 + (((kk*4+quad) ^ (vrow&7))<<4));
        O[j] = __builtin_amdgcn_mfma_f32_16x16x32_bf16(pf[kk], vf, O[j], 0, 0, 0);
      }
    }
  }
#pragma unroll
  for (int j=0;j<4;j++){
#pragma unroll
    for (int r=0;r<4;r++){
      int qa = qt*64 + wid*16 + quad*4 + r;
      float o = O[j][r] / lrun[r];
      Out[(size_t)(b*T_ + qa)*C_ + h*64 + j*16 + l16] = f2bf(o);
    }
  }
}

// ---------------------------------------------------------------------------
extern "C" void kernel_launch(void* const* d_in, const int* in_sizes, int n_in,
                              void* d_out, int out_size, void* d_ws, size_t ws_size,
                              hipStream_t stream)
{
  const float* x       = (const float*)d_in[0];
  const float* ximg    = (const float*)d_in[1];
  const float* ln1_g   = (const float*)d_in[2];
  const float* ln1_b   = (const float*)d_in[3];
  const float* ln2_g   = (const float*)d_in[4];
  const float* ln2_b   = (const float*)d_in[5];
  const float* W_attn  = (const float*)d_in[6];
  const float* b_attn  = (const float*)d_in[7];
  const float* W_aproj = (const float*)d_in[8];
  const float* b_aproj = (const float*)d_in[9];
  const float* Wq = (const float*)d_in[10];
  const float* bq = (const float*)d_in[11];
  const float* Wk = (const float*)d_in[12];
  const float* bk = (const float*)d_in[13];
  const float* Wv = (const float*)d_in[14];
  const float* bv = (const float*)d_in[15];
  const float* Wcproj  = (const float*)d_in[16];
  const float* bcproj  = (const float*)d_in[17];
  const float* W_fc    = (const float*)d_in[18];
  const float* b_fc    = (const float*)d_in[19];
  const float* W_mproj = (const float*)d_in[20];
  const float* b_mproj = (const float*)d_in[21];

  char* ws = (char*)d_ws;
  unsigned short* wt_attn  = (unsigned short*)(ws + 0);
  unsigned short* wt_aproj = (unsigned short*)(ws + 6291456);
  unsigned short* wt_q     = (unsigned short*)(ws + 8388608);
  unsigned short* wt_k     = (unsigned short*)(ws + 10485760);
  unsigned short* wt_v     = (unsigned short*)(ws + 12582912);
  unsigned short* wt_cproj = (unsigned short*)(ws + 14680064);
  unsigned short* wt_fc    = (unsigned short*)(ws + 16777216);
  unsigned short* wt_mproj = (unsigned short*)(ws + 25165824);
  unsigned short* ximg_bf  = (unsigned short*)(ws + 33554432);
  float*          xcur     = (float*)(ws + 37748736);
  unsigned short* h_bf     = (unsigned short*)(ws + 71303168);
  unsigned short* qkv_hm   = (unsigned short*)(ws + 88080384);   // [b,h,3,t,d]
  unsigned short* att_out  = (unsigned short*)(ws + 88080384 + 50331648);
  unsigned short* u_bf     = (unsigned short*)(ws + 88080384);   // aliases qkv (dead by then)
  unsigned short* q2_hm    = (unsigned short*)(ws + 155189248);  // [b,h,t,d]
  unsigned short* kv2_hm   = (unsigned short*)(ws + 171966464);  // [b,h,2,ti,d]
  unsigned short* ca       = (unsigned short*)(ws + 180355072);
  float*          bkv      = (float*)(ws + 197132288);           // concat bk|bv

  dim3 tb(32,8);
  wconv_t5<<<dim3(32,32,5), tb, 0, stream>>>(W_aproj, Wq, Wk, Wv, Wcproj,
                                             wt_aproj, wt_q, wt_k, wt_v, wt_cproj);
  wconv_t<<<dim3(96,32),  tb, 0, stream>>>(W_attn,  wt_attn,  1024, 3072);
  wconv_t<<<dim3(128,32), tb, 0, stream>>>(W_fc,    wt_fc,    1024, 4096);
  wconv_t<<<dim3(32,128), tb, 0, stream>>>(W_mproj, wt_mproj, 4096, 1024);
  conv_bf16<<<BTI_*C_/4/256, 256, 0, stream>>>(ximg, ximg_bf, BTI_*C_/4);
  hipMemcpyAsync(xcur, x, (size_t)BT_*C_*4, hipMemcpyDeviceToDevice, stream);
  hipMemcpyAsync(bkv,        bk, 4096, hipMemcpyDeviceToDevice, stream);
  hipMemcpyAsync(bkv + 1024, bv, 4096, hipMemcpyDeviceToDevice, stream);

  // self-attention
  ln_fwd<<<BT_, 256, 0, stream>>>(x, ln1_g, ln1_b, h_bf);
  gemm_bt<<<dim3(24,64), 256, 0, stream>>>(h_bf, wt_attn, b_attn, nullptr, qkv_hm,
                                           BT_, 3072, 1024, 3, 3, 10);
  attn_fwd<<<2048, 256, 0, stream>>>(qkv_hm, 3*T_*D_, qkv_hm + T_*D_, qkv_hm + 2*T_*D_,
                                     3*T_*D_, 1, 16, att_out, 0.125f);
  gemm_bt<<<dim3(8,64), 256, 0, stream>>>(att_out, wt_aproj, b_aproj, xcur, xcur,
                                          BT_, 1024, 1024, 2, 0, 0);

  // cross-attention
  ln_fwd<<<BT_, 256, 0, stream>>>(xcur, ln1_g, ln1_b, h_bf);
  gemm_bt<<<dim3(8,64), 256, 0, stream>>>(h_bf, wt_q, bq, nullptr, q2_hm,
                                          BT_, 1024, 1024, 3, 1, 10);
  gemm_bt<<<dim3(16,16), 256, 0, stream>>>(ximg_bf, wt_k, bkv, nullptr, kv2_hm,
                                           BTI_, 2048, 1024, 3, 2, 8);
  attn_fwd<<<2048, 256, 0, stream>>>(q2_hm, T_*D_, kv2_hm, kv2_hm + TI_*D_,
                                     2*TI_*D_, 0, 4, ca, 0.125f);
  gemm_bt<<<dim3(8,64), 256, 0, stream>>>(ca, wt_cproj, bcproj, xcur, xcur,
                                          BT_, 1024, 1024, 2, 0, 0);

  // MLP
  ln_fwd<<<BT_, 256, 0, stream>>>(xcur, ln2_g, ln2_b, h_bf);
  gemm_bt<<<dim3(32,64), 256, 0, stream>>>(h_bf, wt_fc, b_fc, nullptr, u_bf,
                                           BT_, 4096, 1024, 1, 0, 0);
  gemm_bt<<<dim3(8,64), 256, 0, stream>>>(u_bf, wt_mproj, b_mproj, xcur, (float*)d_out,
                                          BT_, 1024, 4096, 2, 0, 0);
}

// Round 5
// 722.151 us; speedup vs baseline: 1.2259x; 1.1621x over previous
//
#include <hip/hip_runtime.h>

#define B_ 8
#define T_ 1024
#define C_ 1024
#define H_ 16
#define D_ 64
#define TI_ 256
#define FF_ 4096
#define BT_ (B_*T_)
#define BTI_ (B_*TI_)

typedef __bf16 bf16x8 __attribute__((ext_vector_type(8)));
typedef float f32x4 __attribute__((ext_vector_type(4)));
typedef float f32x16 __attribute__((ext_vector_type(16)));

__device__ __forceinline__ unsigned short f2bf(float f){
  unsigned u = __float_as_uint(f);
  u += 0x7fffu + ((u>>16)&1u);
  return (unsigned short)(u>>16);
}

// async global->LDS, 16B per lane; LDS dest = wave-uniform base + lane*16
__device__ __forceinline__ void cp16(const void* g, void* l){
  __builtin_amdgcn_global_load_lds(
      (const __attribute__((address_space(1))) unsigned int*)(unsigned long long)g,
      (__attribute__((address_space(3))) unsigned int*)(unsigned long long)l,
      16, 0, 0);
}

// ---------------------------------------------------------------------------
// GEMM: C[M,N] = A[M,K](bf16) @ Bt[N,K]^T(bf16) + bias, fused epilogue.
// MODE 1: out bf16 = gelu(v+bias)
// MODE 2: out f32 = resid + v + bias
// MODE 3: out bf16 = v+bias, head-major permute [b,h,kind,t,d]
// 128x128 tile, BK=64, XOR-swizzled LDS chunks, mfma_f32_32x32x16_bf16.
// launch_bounds(256,3): force <=170 regs so 3 blocks/CU fit (acc uses 64
// AGPRs on top of reported VGPRs; at 184 combined we were stuck at 2/CU).
// ---------------------------------------------------------------------------
template<int MODE>
__global__ __launch_bounds__(256, 3) void gemm_bt(
    const unsigned short* __restrict__ A,
    const unsigned short* __restrict__ Bt,
    const float* __restrict__ bias,
    const float* __restrict__ resid,
    void* __restrict__ outp,
    int M, int N, int K, int nkind, int tshift)
{
  __shared__ unsigned short sA[128*64];
  __shared__ unsigned short sB[128*64];
  const int tid  = threadIdx.x;
  const int wid  = tid >> 6;
  const int lane = tid & 63;
  const int l32  = lane & 31;
  const int khalf = lane >> 5;

  const int row0 = blockIdx.y * 128;
  const int col0 = blockIdx.x * 128;
  const int wr = (wid >> 1) * 64;
  const int wc = (wid & 1) * 64;

  // hoisted staging addresses: 8 chunks/thread, pointer-bump by k0 in loop
  const unsigned short* gp[8];
  unsigned short* lp[8];
#pragma unroll
  for (int r=0;r<8;r++){
    int chunk = wid*8 + r;          // 0..31 ; <16 => A-tile, else B-tile
    int cA = chunk & 15;
    int slot = cA*64 + lane;        // 16B slot within tile
    int row = slot >> 3;
    int cc = (slot & 7) ^ (row & 7);
    if (chunk < 16){
      gp[r] = A  + (size_t)(row0+row)*K + cc*8;
      lp[r] = sA + cA*512;
    } else {
      gp[r] = Bt + (size_t)(col0+row)*K + cc*8;
      lp[r] = sB + cA*512;
    }
  }

  f32x16 acc[2][2];
#pragma unroll
  for (int i=0;i<2;i++)
#pragma unroll
    for (int j=0;j<2;j++)
#pragma unroll
      for (int r=0;r<16;r++) acc[i][j][r] = 0.f;

  for (int k0 = 0; k0 < K; k0 += 64){
    if (k0) __syncthreads();
#pragma unroll
    for (int r=0;r<8;r++)
      cp16(gp[r] + k0, lp[r]);
    __syncthreads();
    const char* sAb = (const char*)sA;
    const char* sBb = (const char*)sB;
#pragma unroll
    for (int kk=0;kk<4;kk++){
      bf16x8 af[2], bfb[2];
#pragma unroll
      for (int i=0;i<2;i++){
        int rr = wr + i*32 + l32;
        af[i] = *(const bf16x8*)(sAb + rr*128 + ((((kk<<1)+khalf) ^ (rr&7))<<4));
      }
#pragma unroll
      for (int j=0;j<2;j++){
        int rr = wc + j*32 + l32;
        bfb[j] = *(const bf16x8*)(sBb + rr*128 + ((((kk<<1)+khalf) ^ (rr&7))<<4));
      }
#pragma unroll
      for (int i=0;i<2;i++)
#pragma unroll
        for (int j=0;j<2;j++)
          acc[i][j] = __builtin_amdgcn_mfma_f32_32x32x16_bf16(af[i], bfb[j], acc[i][j], 0, 0, 0);
    }
  }

  // epilogue: C/D layout col=lane&31, row=(reg&3)+8*(reg>>2)+4*(lane>>5)
#pragma unroll
  for (int j=0;j<2;j++){
    int gc = col0 + wc + j*32 + l32;
    float bz = bias[gc];
#pragma unroll
    for (int i=0;i<2;i++){
      int gr_base = row0 + wr + i*32 + 4*khalf;
#pragma unroll
      for (int reg=0; reg<16; ++reg){
        int gr = gr_base + (reg&3) + 8*(reg>>2);
        float v = acc[i][j][reg] + bz;
        if (MODE == 1){
          float w = 1.5957691216057308f*(v + 0.044715f*v*v*v);
          float g = v / (1.f + __expf(-w));
          ((unsigned short*)outp)[(size_t)gr*N + gc] = f2bf(g);
        } else if (MODE == 2){
          size_t idx = (size_t)gr*N + gc;
          ((float*)outp)[idx] = resid[idx] + v;
        } else {
          int kind = gc >> 10;
          int hc = gc & 1023;
          int hh = hc >> 6;
          int d  = hc & 63;
          int bb = gr >> tshift;
          int tt = gr & ((1<<tshift)-1);
          size_t oidx = ((((size_t)(bb*16 + hh)*nkind + kind) << tshift) + tt)*64 + d;
          ((unsigned short*)outp)[oidx] = f2bf(v);
        }
      }
    }
  }
}

// ---------------------------------------------------------------------------
// LayerNorm over C=1024, fp32 in -> bf16 out. One block per row.
// ---------------------------------------------------------------------------
__global__ __launch_bounds__(256) void ln_fwd(
    const float* __restrict__ x, const float* __restrict__ g,
    const float* __restrict__ b, unsigned short* __restrict__ out)
{
  int row = blockIdx.x, t = threadIdx.x;
  const float4* xv = (const float4*)(x + (size_t)row*C_);
  float4 v = xv[t];
  float s  = v.x+v.y+v.z+v.w;
  float ss = v.x*v.x + v.y*v.y + v.z*v.z + v.w*v.w;
#pragma unroll
  for (int o=32;o>0;o>>=1){ s += __shfl_down(s,o); ss += __shfl_down(ss,o); }
  __shared__ float red[16];
  int wid = t>>6, lane = t&63;
  if (lane==0){ red[wid]=s; red[8+wid]=ss; }
  __syncthreads();
  if (t==0){
    red[0] = red[0]+red[1]+red[2]+red[3];
    red[8] = red[8]+red[9]+red[10]+red[11];
  }
  __syncthreads();
  float mu  = red[0] * (1.f/C_);
  float var = red[8] * (1.f/C_) - mu*mu;
  float rstd = rsqrtf(var + 1e-5f);
  float4 gv = ((const float4*)g)[t];
  float4 bv = ((const float4*)b)[t];
  ushort4 o;
  o.x = f2bf((v.x-mu)*rstd*gv.x + bv.x);
  o.y = f2bf((v.y-mu)*rstd*gv.y + bv.y);
  o.z = f2bf((v.z-mu)*rstd*gv.z + bv.z);
  o.w = f2bf((v.w-mu)*rstd*gv.w + bv.w);
  ((ushort4*)(out + (size_t)row*C_))[t] = o;
}

// ---------------------------------------------------------------------------
// Weight transpose+convert: W[Kd,Nd] fp32 -> Wt[Nd,Kd] bf16. 32x32 LDS tile.
// ---------------------------------------------------------------------------
__global__ void wconv_t(const float* __restrict__ W, unsigned short* __restrict__ Wt,
                        int Kd, int Nd)
{
  __shared__ float tile[32][33];
  int tx = threadIdx.x, ty = threadIdx.y;   // 32 x 8
  int n0 = blockIdx.x*32, k0 = blockIdx.y*32;
#pragma unroll
  for (int j=0;j<4;j++)
    tile[ty+8*j][tx] = W[(size_t)(k0+ty+8*j)*Nd + (n0+tx)];
  __syncthreads();
#pragma unroll
  for (int j=0;j<4;j++)
    Wt[(size_t)(n0+ty+8*j)*Kd + (k0+tx)] = f2bf(tile[tx][ty+8*j]);
}

// five 1024x1024 transposes in one launch (z selects the matrix)
__global__ void wconv_t5(const float* W0, const float* W1, const float* W2,
                         const float* W3, const float* W4,
                         unsigned short* O0, unsigned short* O1, unsigned short* O2,
                         unsigned short* O3, unsigned short* O4)
{
  __shared__ float tile[32][33];
  const float* Ws[5] = {W0,W1,W2,W3,W4};
  unsigned short* Os[5] = {O0,O1,O2,O3,O4};
  const float* W = Ws[blockIdx.z];
  unsigned short* Wt = Os[blockIdx.z];
  int tx = threadIdx.x, ty = threadIdx.y;
  int n0 = blockIdx.x*32, k0 = blockIdx.y*32;
#pragma unroll
  for (int j=0;j<4;j++)
    tile[ty+8*j][tx] = W[(size_t)(k0+ty+8*j)*1024 + (n0+tx)];
  __syncthreads();
#pragma unroll
  for (int j=0;j<4;j++)
    Wt[(size_t)(n0+ty+8*j)*1024 + (k0+tx)] = f2bf(tile[tx][ty+8*j]);
}

// fused prologue tail: x->xcur fp32 copy, ximg->bf16 convert, bkv concat
#define PREP_N1 (BT_*C_/4)
#define PREP_N2 (BTI_*C_/4)
__global__ void prep_misc(const float* __restrict__ x, float* __restrict__ xcur,
                          const float* __restrict__ ximg, unsigned short* __restrict__ ximg_bf,
                          const float* __restrict__ bk, const float* __restrict__ bv,
                          float* __restrict__ bkv)
{
  int i = blockIdx.x*256 + threadIdx.x;
  if (i < PREP_N1){
    ((float4*)xcur)[i] = ((const float4*)x)[i];
  } else if (i < PREP_N1 + PREP_N2){
    int k = i - PREP_N1;
    float4 v = ((const float4*)ximg)[k];
    ushort4 o; o.x=f2bf(v.x); o.y=f2bf(v.y); o.z=f2bf(v.z); o.w=f2bf(v.w);
    ((ushort4*)ximg_bf)[k] = o;
  } else if (i < PREP_N1 + PREP_N2 + 512){
    int k = i - PREP_N1 - PREP_N2;
    ((float4*)bkv)[k] = (k < 256) ? ((const float4*)bk)[k] : ((const float4*)bv)[k-256];
  }
}

// ---------------------------------------------------------------------------
// Fused flash attention v4. Head-major inputs: Q/K/V per (b,h) contiguous
// [rows][64]. 1-D grid with XCD-grouping swizzle. 64 q-rows/block, kv-tile
// 64, single-buffer LDS (24KB, 6 blocks/CU), K via global_load_lds,
// V transposed through registers, P via per-wave LDS round-trip, exp2f.
// ---------------------------------------------------------------------------
__global__ __launch_bounds__(256) void attn_fwd(
    const unsigned short* __restrict__ Qb, unsigned int sQ,
    const unsigned short* __restrict__ Kb, const unsigned short* __restrict__ Vb,
    unsigned int sKV, int causal, int nkb_in,
    unsigned short* __restrict__ Out, float scale)
{
  __shared__ unsigned short sK[64*64];
  __shared__ unsigned short sV[64*64];
  __shared__ unsigned short sP[4*16*64];
  const int tid = threadIdx.x;
  const int wid = tid >> 6;
  const int lane = tid & 63;
  const int quad = lane >> 4;
  const int l16 = lane & 15;

  const int L = blockIdx.x;
  const int g  = (L & 7) + (L >> 7) * 8;   // (b,h) group, constant L%8 per group
  const int qt = 15 - ((L >> 3) & 15);     // longest causal blocks first
  const int b = g >> 4, h = g & 15;
  const float c2 = scale * 1.4426950408889634f;

  const unsigned short* Qp = Qb + (size_t)g * sQ;
  const unsigned short* Kp = Kb + (size_t)g * sKV;
  const unsigned short* Vp = Vb + (size_t)g * sKV;

  const int qrow = qt*64 + wid*16 + l16;
  const unsigned short* qb = Qp + (size_t)qrow*64;
  bf16x8 qf[2];
  qf[0] = *(const bf16x8*)(qb + quad*8);
  qf[1] = *(const bf16x8*)(qb + 32 + quad*8);

  f32x4 zero = {0.f,0.f,0.f,0.f};
  f32x4 O[4];
#pragma unroll
  for (int j=0;j<4;j++) O[j] = zero;
  float mrun[4], lrun[4];
#pragma unroll
  for (int r=0;r<4;r++){ mrun[r] = -1e30f; lrun[r] = 0.f; }

  const int nkb = causal ? (qt+1) : nkb_in;
  char* sPw = (char*)sP + wid*2048;

  for (int kb=0; kb<nkb; ++kb){
    if (kb) __syncthreads();
#pragma unroll
    for (int ss=0; ss<2; ++ss){
      int slot = tid + ss*256;
      int srow = slot >> 3;
      int cc = (slot & 7) ^ (srow & 7);
      cp16(Kp + (size_t)kb*4096 + srow*64 + cc*8, sK + (size_t)(wid*64 + ss*256)*8);
    }
    {
      int s_ = lane;
      int dbase = wid*16;
      const unsigned short* gv = Vp + (size_t)kb*4096 + s_*64 + dbase;
      unsigned short vals[16];
      *(uint4*)(vals)   = *(const uint4*)(gv);
      *(uint4*)(vals+8) = *(const uint4*)(gv+8);
      int chunk = s_ >> 3;
      int sb = (s_ & 7)*2;
#pragma unroll
      for (int jj=0; jj<16; ++jj){
        int d = dbase + jj;
        *(unsigned short*)((char*)sV + d*128 + ((chunk ^ (d&7))<<4) + sb) = vals[jj];
      }
    }
    __syncthreads();

    f32x4 sacc[4];
#pragma unroll
    for (int j=0;j<4;j++) sacc[j] = zero;
#pragma unroll
    for (int j=0;j<4;j++){
      int krow = j*16 + l16;
#pragma unroll
      for (int kk=0;kk<2;kk++){
        bf16x8 kf = *(const bf16x8*)((const char*)sK + krow*128 + (((kk*4+quad) ^ (krow&7))<<4));
        sacc[j] = __builtin_amdgcn_mfma_f32_16x16x32_bf16(qf[kk], kf, sacc[j], 0, 0, 0);
      }
    }
    const int qa0 = qt*64 + wid*16 + quad*4;
    float sc[4][4];
#pragma unroll
    for (int j=0;j<4;j++){
      int key = kb*64 + j*16 + l16;
#pragma unroll
      for (int r=0;r<4;r++){
        float v = sacc[j][r];
        if (causal && key > qa0 + r) v = -1e30f;
        sc[j][r] = v;
      }
    }
    float mnew[4], alpha[4], rs[4];
#pragma unroll
    for (int r=0;r<4;r++){
      float m = fmaxf(fmaxf(sc[0][r], sc[1][r]), fmaxf(sc[2][r], sc[3][r]));
#pragma unroll
      for (int msk=1; msk<16; msk<<=1) m = fmaxf(m, __shfl_xor(m, msk));
      mnew[r] = fmaxf(mrun[r], m);
      alpha[r] = exp2f((mrun[r] - mnew[r]) * c2);
      mrun[r] = mnew[r];
      rs[r] = 0.f;
    }
#pragma unroll
    for (int j=0;j<4;j++){
#pragma unroll
      for (int r=0;r<4;r++){
        float p = exp2f((sc[j][r] - mnew[r]) * c2);
        rs[r] += p;
        int prow = quad*4 + r;
        int cole = j*16 + l16;
        *(unsigned short*)(sPw + prow*128 + (((cole>>3) ^ (prow&7))<<4) + (cole&7)*2) = f2bf(p);
      }
    }
#pragma unroll
    for (int r=0;r<4;r++){
#pragma unroll
      for (int msk=1; msk<16; msk<<=1) rs[r] += __shfl_xor(rs[r], msk);
      lrun[r] = lrun[r]*alpha[r] + rs[r];
    }
#pragma unroll
    for (int j=0;j<4;j++){
      O[j][0] *= alpha[0]; O[j][1] *= alpha[1];
      O[j][2] *= alpha[2]; O[j][3] *= alpha[3];
    }
    bf16x8 pf[2];
#pragma unroll
    for (int kk=0;kk<2;kk++)
      pf[kk] = *(const bf16x8*)(sPw + l16*128 + (((kk*4+quad) ^ (l16&7))<<4));
#pragma unroll
    for (int j=0;j<4;j++){
      int vrow = j*16 + l16;
#pragma unroll
      for (int kk=0;kk<2;kk++){
        bf16x8 vf = *(const bf16x8*)((const char*)sV + vrow*128 + (((kk*4+quad) ^ (vrow&7))<<4));
        O[j] = __builtin_amdgcn_mfma_f32_16x16x32_bf16(pf[kk], vf, O[j], 0, 0, 0);
      }
    }
  }
#pragma unroll
  for (int j=0;j<4;j++){
#pragma unroll
    for (int r=0;r<4;r++){
      int qa = qt*64 + wid*16 + quad*4 + r;
      float o = O[j][r] / lrun[r];
      Out[(size_t)(b*T_ + qa)*C_ + h*64 + j*16 + l16] = f2bf(o);
    }
  }
}

// ---------------------------------------------------------------------------
extern "C" void kernel_launch(void* const* d_in, const int* in_sizes, int n_in,
                              void* d_out, int out_size, void* d_ws, size_t ws_size,
                              hipStream_t stream)
{
  const float* x       = (const float*)d_in[0];
  const float* ximg    = (const float*)d_in[1];
  const float* ln1_g   = (const float*)d_in[2];
  const float* ln1_b   = (const float*)d_in[3];
  const float* ln2_g   = (const float*)d_in[4];
  const float* ln2_b   = (const float*)d_in[5];
  const float* W_attn  = (const float*)d_in[6];
  const float* b_attn  = (const float*)d_in[7];
  const float* W_aproj = (const float*)d_in[8];
  const float* b_aproj = (const float*)d_in[9];
  const float* Wq = (const float*)d_in[10];
  const float* bq = (const float*)d_in[11];
  const float* Wk = (const float*)d_in[12];
  const float* bk = (const float*)d_in[13];
  const float* Wv = (const float*)d_in[14];
  const float* bv = (const float*)d_in[15];
  const float* Wcproj  = (const float*)d_in[16];
  const float* bcproj  = (const float*)d_in[17];
  const float* W_fc    = (const float*)d_in[18];
  const float* b_fc    = (const float*)d_in[19];
  const float* W_mproj = (const float*)d_in[20];
  const float* b_mproj = (const float*)d_in[21];

  char* ws = (char*)d_ws;
  unsigned short* wt_attn  = (unsigned short*)(ws + 0);
  unsigned short* wt_aproj = (unsigned short*)(ws + 6291456);
  unsigned short* wt_q     = (unsigned short*)(ws + 8388608);
  unsigned short* wt_k     = (unsigned short*)(ws + 10485760);
  unsigned short* wt_v     = (unsigned short*)(ws + 12582912);
  unsigned short* wt_cproj = (unsigned short*)(ws + 14680064);
  unsigned short* wt_fc    = (unsigned short*)(ws + 16777216);
  unsigned short* wt_mproj = (unsigned short*)(ws + 25165824);
  unsigned short* ximg_bf  = (unsigned short*)(ws + 33554432);
  float*          xcur     = (float*)(ws + 37748736);
  unsigned short* h_bf     = (unsigned short*)(ws + 71303168);
  unsigned short* qkv_hm   = (unsigned short*)(ws + 88080384);   // [b,h,3,t,d]
  unsigned short* att_out  = (unsigned short*)(ws + 88080384 + 50331648);
  unsigned short* u_bf     = (unsigned short*)(ws + 88080384);   // aliases qkv (dead by then)
  unsigned short* q2_hm    = (unsigned short*)(ws + 155189248);  // [b,h,t,d]
  unsigned short* kv2_hm   = (unsigned short*)(ws + 171966464);  // [b,h,2,ti,d]
  unsigned short* ca       = (unsigned short*)(ws + 180355072);
  float*          bkv      = (float*)(ws + 197132288);           // concat bk|bv

  dim3 tb(32,8);
  wconv_t5<<<dim3(32,32,5), tb, 0, stream>>>(W_aproj, Wq, Wk, Wv, Wcproj,
                                             wt_aproj, wt_q, wt_k, wt_v, wt_cproj);
  wconv_t<<<dim3(96,32),  tb, 0, stream>>>(W_attn,  wt_attn,  1024, 3072);
  wconv_t<<<dim3(128,32), tb, 0, stream>>>(W_fc,    wt_fc,    1024, 4096);
  wconv_t<<<dim3(32,128), tb, 0, stream>>>(W_mproj, wt_mproj, 4096, 1024);
  prep_misc<<<(PREP_N1+PREP_N2+512+255)/256, 256, 0, stream>>>(
      x, xcur, ximg, ximg_bf, bk, bv, bkv);

  // self-attention
  ln_fwd<<<BT_, 256, 0, stream>>>(x, ln1_g, ln1_b, h_bf);
  gemm_bt<3><<<dim3(24,64), 256, 0, stream>>>(h_bf, wt_attn, b_attn, nullptr, qkv_hm,
                                              BT_, 3072, 1024, 3, 10);
  attn_fwd<<<2048, 256, 0, stream>>>(qkv_hm, 3*T_*D_, qkv_hm + T_*D_, qkv_hm + 2*T_*D_,
                                     3*T_*D_, 1, 16, att_out, 0.125f);
  gemm_bt<2><<<dim3(8,64), 256, 0, stream>>>(att_out, wt_aproj, b_aproj, xcur, xcur,
                                             BT_, 1024, 1024, 0, 0);

  // cross-attention
  ln_fwd<<<BT_, 256, 0, stream>>>(xcur, ln1_g, ln1_b, h_bf);
  gemm_bt<3><<<dim3(8,64), 256, 0, stream>>>(h_bf, wt_q, bq, nullptr, q2_hm,
                                             BT_, 1024, 1024, 1, 10);
  gemm_bt<3><<<dim3(16,16), 256, 0, stream>>>(ximg_bf, wt_k, bkv, nullptr, kv2_hm,
                                              BTI_, 2048, 1024, 2, 8);
  attn_fwd<<<2048, 256, 0, stream>>>(q2_hm, T_*D_, kv2_hm, kv2_hm + TI_*D_,
                                     2*TI_*D_, 0, 4, ca, 0.125f);
  gemm_bt<2><<<dim3(8,64), 256, 0, stream>>>(ca, wt_cproj, bcproj, xcur, xcur,
                                             BT_, 1024, 1024, 0, 0);

  // MLP
  ln_fwd<<<BT_, 256, 0, stream>>>(xcur, ln2_g, ln2_b, h_bf);
  gemm_bt<1><<<dim3(32,64), 256, 0, stream>>>(h_bf, wt_fc, b_fc, nullptr, u_bf,
                                              BT_, 4096, 1024, 0, 0);
  gemm_bt<2><<<dim3(8,64), 256, 0, stream>>>(u_bf, wt_mproj, b_mproj, xcur, (float*)d_out,
                                             BT_, 1024, 4096, 0, 0);
}